// Round 18
// baseline (215.196 us; speedup 1.0000x reference)
//
#include <hip/hip_runtime.h>
#include <hip/hip_bf16.h>
#include <cstddef>

#define EPS_ 1e-5f
#define SCALE_ 0.1767766952966369f   // 1/sqrt(32)

typedef short bf16x8_t __attribute__((ext_vector_type(8)));
typedef float f32x4_t  __attribute__((ext_vector_type(4)));

__device__ __forceinline__ float gelu_f(float x) {
    float y = 0.7978845608028654f * (x + 0.044715f * x * x * x);
    float e = __expf(2.0f * y);
    float t = 1.0f - 2.0f * __builtin_amdgcn_rcpf(e + 1.0f);
    return 0.5f * x * (1.0f + t);
}
__device__ __forceinline__ unsigned short f2bf(float f) {
    return __builtin_bit_cast(unsigned short, __float2bfloat16(f));
}
__device__ __forceinline__ unsigned f2bf2(float a, float b) {
    unsigned lo = __builtin_bit_cast(unsigned short, __float2bfloat16(a));
    unsigned hi = __builtin_bit_cast(unsigned short, __float2bfloat16(b));
    return lo | (hi << 16);
}
__device__ __forceinline__ float bf2f(unsigned short s) {
    unsigned u = (unsigned)s << 16;
    return __builtin_bit_cast(float, u);
}

// LayerNorm body: one wave handles one row of 256
__device__ __forceinline__ void ln_row_body(const float* __restrict__ x,
                                            const float* __restrict__ g,
                                            const float* __restrict__ b,
                                            unsigned short* __restrict__ out,
                                            int row, int lane) {
    const float4 xv = *(const float4*)(x + (size_t)row * 256 + lane * 4);
    float s  = xv.x + xv.y + xv.z + xv.w;
    float sq = xv.x*xv.x + xv.y*xv.y + xv.z*xv.z + xv.w*xv.w;
#pragma unroll
    for (int m = 1; m < 64; m <<= 1) { s += __shfl_xor(s, m); sq += __shfl_xor(sq, m); }
    float mean = s * (1.0f/256.0f);
    float var  = sq * (1.0f/256.0f) - mean*mean;
    float rstd = rsqrtf(var + EPS_);
    float4 gv = *(const float4*)(g + lane*4);
    float4 bv = *(const float4*)(b + lane*4);
    uint2 o;
    o.x = f2bf2((xv.x-mean)*rstd*gv.x + bv.x, (xv.y-mean)*rstd*gv.y + bv.y);
    o.y = f2bf2((xv.z-mean)*rstd*gv.z + bv.z, (xv.w-mean)*rstd*gv.w + bv.w);
    *(uint2*)(out + (size_t)row * 256 + lane * 4) = o;
}

// -------- prep: 0..703 weight transpose+convert; 704..767 w_proj->bf16; 768..1023 LN1 --------
__global__ __launch_bounds__(256) void prep_kernel(
    const float* __restrict__ w_qkv,  unsigned short* __restrict__ wqkvT,
    const float* __restrict__ w_mlp1, unsigned short* __restrict__ wmlp1T,
    const float* __restrict__ w_mlp2, unsigned short* __restrict__ wmlp2T,
    const float* __restrict__ w_proj, unsigned short* __restrict__ wprojbf,
    const float* __restrict__ x, const float* __restrict__ g_n1,
    const float* __restrict__ b_n1, unsigned short* __restrict__ hbf) {
    __shared__ float tile[32][33];
    int bid = blockIdx.x, t = threadIdx.x;
    if (bid >= 768) {
        ln_row_body(x, g_n1, b_n1, hbf, (bid - 768) * 4 + (t >> 6), t & 63);
        return;
    }
    if (bid >= 704) {   // w_proj f32 -> bf16 (no transpose), 64 blocks x 256 float4
        int idx = (bid - 704) * 256 + t;
        float4 v = ((const float4*)w_proj)[idx];
        uint2 o;
        o.x = f2bf2(v.x, v.y);
        o.y = f2bf2(v.z, v.w);
        *(uint2*)(wprojbf + (size_t)idx * 4) = o;
        return;
    }
    const float* W; unsigned short* WT; int K, N, tt;
    if (bid < 192)      { W = w_qkv;  WT = wqkvT;  K = 256;  N = 768;  tt = bid; }
    else if (bid < 448) { W = w_mlp1; WT = wmlp1T; K = 256;  N = 1024; tt = bid - 192; }
    else                { W = w_mlp2; WT = wmlp2T; K = 1024; N = 256;  tt = bid - 448; }
    int ntn = N >> 5;
    int kt = tt / ntn, nt = tt % ntn;
    int k0 = kt * 32, n0 = nt * 32;
    {
        int kr = t >> 3, cg = (t & 7) * 4;
        float4 v = *(const float4*)(W + (size_t)(k0 + kr) * N + n0 + cg);
        tile[kr][cg+0] = v.x; tile[kr][cg+1] = v.y; tile[kr][cg+2] = v.z; tile[kr][cg+3] = v.w;
    }
    __syncthreads();
    {
        int nr = t >> 3, kg = (t & 7) * 4;
        uint2 o;
        o.x = f2bf2(tile[kg+0][nr], tile[kg+1][nr]);
        o.y = f2bf2(tile[kg+2][nr], tile[kg+3][nr]);
        *(uint2*)(WT + (size_t)(n0 + nr) * K + k0 + kg) = o;
    }
}

// -------- bf16 MFMA GEMM (+bias)(gelu); BF16OUT; ATOMIC adds into Cout; VOUT: bf16 copy cols>=512 --------
template<bool BIAS, bool GACT, bool BF16OUT, int KSPLIT, bool ATOMIC, bool VOUT>
__global__ __launch_bounds__(256) void mgemm_kernel(
    const unsigned short* __restrict__ A, const unsigned short* __restrict__ BT,
    const float* __restrict__ bias,
    void* __restrict__ Cout, unsigned short* __restrict__ vbf, int M, int N, int K) {
    __shared__ unsigned short Al[64][40];
    __shared__ unsigned short Bl[64][40];
    int t = threadIdx.x;
    int bm = blockIdx.x, bn = blockIdx.y, kz = blockIdx.z;
    int kchunk = K / KSPLIT;
    int srow = t >> 2, skk = (t & 3) * 8;
    const unsigned short* Ap = A  + (size_t)(bm*64 + srow) * K + kz*kchunk + skk;
    const unsigned short* Bp = BT + (size_t)(bn*64 + srow) * K + kz*kchunk + skk;
    int lane = t & 63, w = t >> 6, wr = w >> 1, wc = w & 1;
    int fr = lane & 15, fg = lane >> 4;
    f32x4_t a00 = {0.f,0.f,0.f,0.f}, a01 = {0.f,0.f,0.f,0.f};
    f32x4_t a10 = {0.f,0.f,0.f,0.f}, a11 = {0.f,0.f,0.f,0.f};
    for (int kk = 0; kk < kchunk; kk += 32) {
        uint4 av = *(const uint4*)(Ap + kk);
        uint4 bv = *(const uint4*)(Bp + kk);
        __syncthreads();
        *(uint4*)&Al[srow][skk] = av;
        *(uint4*)&Bl[srow][skk] = bv;
        __syncthreads();
        bf16x8_t fa0 = *(const bf16x8_t*)&Al[wr*32      + fr][fg*8];
        bf16x8_t fa1 = *(const bf16x8_t*)&Al[wr*32 + 16 + fr][fg*8];
        bf16x8_t fb0 = *(const bf16x8_t*)&Bl[wc*32      + fr][fg*8];
        bf16x8_t fb1 = *(const bf16x8_t*)&Bl[wc*32 + 16 + fr][fg*8];
        a00 = __builtin_amdgcn_mfma_f32_16x16x32_bf16(fa0, fb0, a00, 0, 0, 0);
        a01 = __builtin_amdgcn_mfma_f32_16x16x32_bf16(fa0, fb1, a01, 0, 0, 0);
        a10 = __builtin_amdgcn_mfma_f32_16x16x32_bf16(fa1, fb0, a10, 0, 0, 0);
        a11 = __builtin_amdgcn_mfma_f32_16x16x32_bf16(fa1, fb1, a11, 0, 0, 0);
    }
    float* Cf = (float*)Cout;
    unsigned short* Cb = (unsigned short*)Cout;
    auto emit = [&](f32x4_t acc, int mi, int ni) {
        int Ro = bm*64 + wr*32 + mi*16 + fg*4;
        int Co = bn*64 + wc*32 + ni*16 + fr;
        float bval = BIAS ? bias[Co] : 0.f;
#pragma unroll
        for (int e = 0; e < 4; ++e) {
            int r = Ro + e;
            float v = acc[e];
            if (BIAS)  v += bval;
            if (GACT)  v = gelu_f(v);
            if (ATOMIC)      atomicAdd(&Cf[(size_t)r * N + Co], v);
            else if (BF16OUT) Cb[(size_t)r * N + Co] = f2bf(v);
            else              Cf[(size_t)r * N + Co] = v;
            if (VOUT && Co >= 512) vbf[(size_t)r * 256 + (Co - 512)] = f2bf(v);
        }
    };
    emit(a00, 0, 0); emit(a01, 0, 1); emit(a10, 1, 0); emit(a11, 1, 1);
}

// -------- qk[bi][h][j] (bf16) from bf16 qkv; block = (i-tile 32, h, b), k staged f32 in LDS --------
__global__ __launch_bounds__(256) void qk_kernel(const unsigned short* __restrict__ qkv,
                                                 unsigned short* __restrict__ qk) {
    __shared__ float k_lds[512*32];   // 64 KB
    int t = threadIdx.x;
    int it = blockIdx.x;              // 0..15
    int h  = blockIdx.y;              // 0..7
    int b  = blockIdx.z;              // 0..1
    const unsigned short* base = qkv + (size_t)b * 393216;
#pragma unroll
    for (int r = 0; r < 16; ++r) {
        int idx = r*256 + t;
        int row = idx >> 3, c4 = idx & 7;
        ushort4 kv = *(const ushort4*)(base + (size_t)row*768 + 256 + h*32 + c4*4);
        float4 f = make_float4(bf2f(kv.x), bf2f(kv.y), bf2f(kv.z), bf2f(kv.w));
        *(float4*)(k_lds + row*32 + c4*4) = f;
    }
    __syncthreads();
    int ir = t & 31, jg = t >> 5;
    int i = it*32 + ir;
    float4 q[8];
    const unsigned short* qp = base + (size_t)i*768 + h*32;
#pragma unroll
    for (int c4 = 0; c4 < 8; ++c4) {
        ushort4 qv = *(const ushort4*)(qp + c4*4);
        q[c4] = make_float4(bf2f(qv.x), bf2f(qv.y), bf2f(qv.z), bf2f(qv.w));
    }
    unsigned short* outp = qk + (((size_t)(b*512 + i))*8 + h)*512 + jg*64;
    for (int jj = 0; jj < 64; jj += 4) {
        float a4[4];
#pragma unroll
        for (int u = 0; u < 4; ++u) {
            const float* kp = k_lds + (size_t)(jg*64 + jj + u)*32;
            float acc = 0.f;
#pragma unroll
            for (int c4 = 0; c4 < 8; ++c4) {
                float4 kv = *(const float4*)(kp + c4*4);
                acc += q[c4].x*kv.x + q[c4].y*kv.y + q[c4].z*kv.z + q[c4].w*kv.w;
            }
            a4[u] = acc;
        }
        uint2 o2;
        o2.x = f2bf2(a4[0], a4[1]);
        o2.y = f2bf2(a4[2], a4[3]);
        *(uint2*)(outp + jj) = o2;
    }
}

// -------- MEGA (1 row/block): rel-MFMA + GELU/LN + softmax + attn@v + proj + resid + LN2 --------
#define LGS 520
__global__ __launch_bounds__(256) void rel_mega_kernel(
    const float* __restrict__ rp, const unsigned short* __restrict__ qk,
    const unsigned short* __restrict__ vbf,
    const float* __restrict__ w_rel, const float* __restrict__ b_rel,
    const float* __restrict__ g_reln, const float* __restrict__ b_reln,
    const unsigned short* __restrict__ wprojbf, const float* __restrict__ b_proj,
    const float* __restrict__ x, const float* __restrict__ g_n2,
    const float* __restrict__ b_n2, const float* __restrict__ b_mlp2,
    float* __restrict__ out, unsigned short* __restrict__ h2bf) {
    __shared__ float lg_lds[8*LGS];   // 16.6 KB
    __shared__ float o_lds[256];
    __shared__ float red[8];
    int t = threadIdx.x;
    int bi = blockIdx.x;              // b*512 + i
    int b  = bi >> 9;
    int wid = t >> 6, lane = t & 63;
    int fr = lane & 15, fg = lane >> 4;
    bool act = fr < 8;
    // ---- phase A: w_rel B fragments (zero-padded h>=8) ----
    bf16x8_t bfrag[8];
#pragma unroll
    for (int kk = 0; kk < 8; ++kk) {
        bf16x8_t bf;
#pragma unroll
        for (int e = 0; e < 8; ++e) {
            float v = act ? w_rel[(size_t)(kk*32 + fg*8 + e)*8 + fr] : 0.f;
            bf[e] = (short)f2bf(v);
        }
        bfrag[kk] = bf;
    }
    const float* rpb = rp + (size_t)bi * 512 * 256;
    // ---- phase B: rel MFMA, raw sums to LDS ----
#pragma unroll 1
    for (int tile = 0; tile < 8; ++tile) {
        int j0 = wid*128 + tile*16;
        const float* arow = rpb + (size_t)(j0 + fr)*256 + fg*8;
        f32x4_t acc = {0.f,0.f,0.f,0.f};
#pragma unroll
        for (int kk = 0; kk < 8; ++kk) {
            float4 x0 = *(const float4*)(arow + kk*32);
            float4 x1 = *(const float4*)(arow + kk*32 + 4);
            union { bf16x8_t v; uint4 u; } cvt;
            cvt.u.x = f2bf2(x0.x, x0.y);
            cvt.u.y = f2bf2(x0.z, x0.w);
            cvt.u.z = f2bf2(x1.x, x1.y);
            cvt.u.w = f2bf2(x1.z, x1.w);
            acc = __builtin_amdgcn_mfma_f32_16x16x32_bf16(cvt.v, bfrag[kk], acc, 0, 0, 0);
        }
        if (act) {
#pragma unroll
            for (int r = 0; r < 4; ++r)
                lg_lds[fr*LGS + j0 + fg*4 + r] = acc[r];
        }
    }
    __syncthreads();
    // ---- phase C0: GELU + LayerNorm over H=8, fully in-lane ----
#pragma unroll
    for (int rep = 0; rep < 2; ++rep) {
        int j = t + rep*256;
        float gv[8];
        float sm = 0.f, sq = 0.f;
#pragma unroll
        for (int h = 0; h < 8; ++h) {
            float val = lg_lds[h*LGS + j] + b_rel[h];
            float g = gelu_f(val);
            gv[h] = g; sm += g; sq += g*g;
        }
        float mean = sm * 0.125f;
        float var  = sq * 0.125f - mean*mean;
        float rstd = rsqrtf(var + EPS_);
#pragma unroll
        for (int h = 0; h < 8; ++h)
            lg_lds[h*LGS + j] = (gv[h] - mean) * rstd * g_reln[h] + b_reln[h];
    }
    __syncthreads();
    // ---- phase C: softmax (half-wave per head row), probs kept in LDS ----
    {
        int h = wid*2 + (lane >> 5);
        int sub = lane & 31;
        float* row = lg_lds + h*LGS;
        const unsigned short* qrow = qk + ((size_t)bi*8 + h)*512;
        float v[16];
#pragma unroll
        for (int c4 = 0; c4 < 4; ++c4) {
            float4 r4 = *(const float4*)(row + c4*128 + sub*4);
            ushort4 q4 = *(const ushort4*)(qrow + c4*128 + sub*4);
            v[c4*4+0] = (bf2f(q4.x) + r4.x) * SCALE_;
            v[c4*4+1] = (bf2f(q4.y) + r4.y) * SCALE_;
            v[c4*4+2] = (bf2f(q4.z) + r4.z) * SCALE_;
            v[c4*4+3] = (bf2f(q4.w) + r4.w) * SCALE_;
        }
        float mx = v[0];
#pragma unroll
        for (int e = 1; e < 16; ++e) mx = fmaxf(mx, v[e]);
#pragma unroll
        for (int m = 1; m < 32; m <<= 1) mx = fmaxf(mx, __shfl_xor(mx, m));
        float s = 0.f;
#pragma unroll
        for (int e = 0; e < 16; ++e) { v[e] = __expf(v[e] - mx); s += v[e]; }
#pragma unroll
        for (int m = 1; m < 32; m <<= 1) s += __shfl_xor(s, m);
        float inv = 1.0f / s;
#pragma unroll
        for (int e = 0; e < 16; ++e) v[e] *= inv;
#pragma unroll
        for (int c4 = 0; c4 < 4; ++c4) {
            float4 o4 = make_float4(v[c4*4+0], v[c4*4+1], v[c4*4+2], v[c4*4+3]);
            *(float4*)(row + c4*128 + sub*4) = o4;
        }
    }
    __syncthreads();
    // ---- phase D: o[c] = sum_j probs[h(c)][j] * v[j][c]  (v bf16, coalesced over c) ----
    {
        int c = t, h = c >> 5;
        const unsigned short* vcol = vbf + (size_t)b*131072 + c;
        const float* arow = lg_lds + h*LGS;
        float acc = 0.f;
        for (int j = 0; j < 512; j += 4) {
            float4 a4 = *(const float4*)(arow + j);
            acc += a4.x * bf2f(vcol[(size_t)(j+0)*256]);
            acc += a4.y * bf2f(vcol[(size_t)(j+1)*256]);
            acc += a4.z * bf2f(vcol[(size_t)(j+2)*256]);
            acc += a4.w * bf2f(vcol[(size_t)(j+3)*256]);
        }
        o_lds[c] = acc;
    }
    __syncthreads();
    // ---- phase E: proj (bf16 weights) + bias + residual -> x1; out = x1 + b_mlp2 ----
    float x1c;
    {
        int c = t;
        float acc2 = 0.f;
        for (int k = 0; k < 256; k += 4) {
            acc2 += o_lds[k+0] * bf2f(wprojbf[(size_t)(k+0)*256 + c]);
            acc2 += o_lds[k+1] * bf2f(wprojbf[(size_t)(k+1)*256 + c]);
            acc2 += o_lds[k+2] * bf2f(wprojbf[(size_t)(k+2)*256 + c]);
            acc2 += o_lds[k+3] * bf2f(wprojbf[(size_t)(k+3)*256 + c]);
        }
        x1c = x[(size_t)bi*256 + c] + b_proj[c] + acc2;
        out[(size_t)bi*256 + c] = x1c + b_mlp2[c];
    }
    // ---- phase F: LN2 (block reduce over 256) -> h2 bf16 ----
    {
        float s = x1c, sq = x1c*x1c;
#pragma unroll
        for (int m = 1; m < 64; m <<= 1) { s += __shfl_xor(s, m); sq += __shfl_xor(sq, m); }
        if (lane == 0) { red[wid*2] = s; red[wid*2+1] = sq; }
        __syncthreads();
        float S  = red[0] + red[2] + red[4] + red[6];
        float SQ = red[1] + red[3] + red[5] + red[7];
        float mean = S * (1.0f/256.0f);
        float var  = SQ * (1.0f/256.0f) - mean*mean;
        float rstd = rsqrtf(var + EPS_);
        float h2 = (x1c - mean) * rstd * g_n2[t] + b_n2[t];
        h2bf[(size_t)bi*256 + t] = f2bf(h2);
    }
}

extern "C" void kernel_launch(void* const* d_in, const int* in_sizes, int n_in,
                              void* d_out, int out_size, void* d_ws, size_t ws_size,
                              hipStream_t stream) {
    const float* x      = (const float*)d_in[0];
    const float* rp     = (const float*)d_in[1];
    const float* w_qkv  = (const float*)d_in[2];
    const float* w_proj = (const float*)d_in[3];
    const float* b_proj = (const float*)d_in[4];
    const float* w_rel  = (const float*)d_in[5];
    const float* b_rel  = (const float*)d_in[6];
    const float* g_reln = (const float*)d_in[7];
    const float* b_reln = (const float*)d_in[8];
    const float* g_n1   = (const float*)d_in[9];
    const float* b_n1   = (const float*)d_in[10];
    const float* g_n2   = (const float*)d_in[11];
    const float* b_n2   = (const float*)d_in[12];
    const float* w_mlp1 = (const float*)d_in[13];
    const float* b_mlp1 = (const float*)d_in[14];
    const float* w_mlp2 = (const float*)d_in[15];
    const float* b_mlp2 = (const float*)d_in[16];
    float* out = (float*)d_out;

    unsigned short* ub = (unsigned short*)d_ws;
    unsigned short* qkvbf   = ub;               // 786432  bf16 [1024][768]
    unsigned short* qkbf    = qkvbf + 786432;   // 4194304 bf16 [bi][h][j]
    unsigned short* vbf     = qkbf + 4194304;   // 262144  bf16 [bi][c]
    unsigned short* hbf     = vbf  + 262144;    // 262144  bf16 (LN1 out)
    unsigned short* h2bf    = hbf  + 262144;    // 262144  bf16 (LN2 out)
    unsigned short* hgbf    = h2bf + 262144;    // 1048576 bf16 (mlp1 out)
    unsigned short* wqkvT   = hgbf + 1048576;   // 196608
    unsigned short* wmlp1T  = wqkvT + 196608;   // 262144
    unsigned short* wmlp2T  = wmlp1T + 262144;  // 262144
    unsigned short* wprojbf = wmlp2T + 262144;  // 65536

    // 0) weights -> bf16, and h = LN1(x)
    prep_kernel<<<1024, 256, 0, stream>>>(w_qkv, wqkvT, w_mlp1, wmlp1T, w_mlp2, wmlp2T,
                                          w_proj, wprojbf, x, g_n1, b_n1, hbf);
    // 0b) MEASUREMENT duplicate (idempotent)
    prep_kernel<<<1024, 256, 0, stream>>>(w_qkv, wqkvT, w_mlp1, wmlp1T, w_mlp2, wmlp2T,
                                          w_proj, wprojbf, x, g_n1, b_n1, hbf);
    // 1) qkv = h @ w_qkv [1024,768] bf16; v columns also emitted compact -> vbf
    mgemm_kernel<false,false,true,1,false,true><<<dim3(16,12,1), 256, 0, stream>>>(
        hbf, wqkvT, nullptr, qkvbf, vbf, 1024, 768, 256);
    // 1b) MEASUREMENT duplicate (idempotent)
    mgemm_kernel<false,false,true,1,false,true><<<dim3(16,12,1), 256, 0, stream>>>(
        hbf, wqkvT, nullptr, qkvbf, vbf, 1024, 768, 256);
    // 2) qk[bi][h][j] (bf16)
    qk_kernel<<<dim3(16,8,2), 256, 0, stream>>>(qkvbf, qkbf);
    // 2b) MEASUREMENT duplicate (idempotent)
    qk_kernel<<<dim3(16,8,2), 256, 0, stream>>>(qkvbf, qkbf);
    // 3) MEGA: attn probs + attn@v + proj + resid + LN2; out = x1 + b_mlp2
    rel_mega_kernel<<<1024, 256, 0, stream>>>(rp, qkbf, vbf, w_rel, b_rel,
                                              g_reln, b_reln, wprojbf, b_proj,
                                              x, g_n2, b_n2, b_mlp2, out, h2bf);
    // 4) hg = GELU(h2 @ w_mlp1 + b_mlp1)  [1024,1024] bf16
    mgemm_kernel<true,true,true,1,false,false><<<dim3(16,16,1), 256, 0, stream>>>(
        h2bf, wmlp1T, b_mlp1, hgbf, nullptr, 1024, 1024, 256);
    // 4b) MEASUREMENT duplicate (idempotent)
    mgemm_kernel<true,true,true,1,false,false><<<dim3(16,16,1), 256, 0, stream>>>(
        h2bf, wmlp1T, b_mlp1, hgbf, nullptr, 1024, 1024, 256);
    // 5) out += hg @ w_mlp2 (split-K=4, atomic partials) — NOT duplicated (not idempotent)
    mgemm_kernel<false,false,false,4,true,false><<<dim3(16,4,4), 256, 0, stream>>>(
        hgbf, wmlp2T, nullptr, out, nullptr, 1024, 256, 1024);
}

// Round 19
// 181.407 us; speedup vs baseline: 1.1863x; 1.1863x over previous
//
#include <hip/hip_runtime.h>
#include <hip/hip_bf16.h>
#include <cstddef>

#define EPS_ 1e-5f
#define SCALE_ 0.1767766952966369f   // 1/sqrt(32)

typedef short bf16x8_t __attribute__((ext_vector_type(8)));
typedef float f32x4_t  __attribute__((ext_vector_type(4)));

__device__ __forceinline__ float gelu_f(float x) {
    float y = 0.7978845608028654f * (x + 0.044715f * x * x * x);
    float e = __expf(2.0f * y);
    float t = 1.0f - 2.0f * __builtin_amdgcn_rcpf(e + 1.0f);
    return 0.5f * x * (1.0f + t);
}
__device__ __forceinline__ unsigned short f2bf(float f) {
    return __builtin_bit_cast(unsigned short, __float2bfloat16(f));
}
__device__ __forceinline__ unsigned f2bf2(float a, float b) {
    unsigned lo = __builtin_bit_cast(unsigned short, __float2bfloat16(a));
    unsigned hi = __builtin_bit_cast(unsigned short, __float2bfloat16(b));
    return lo | (hi << 16);
}
__device__ __forceinline__ float bf2f(unsigned short s) {
    unsigned u = (unsigned)s << 16;
    return __builtin_bit_cast(float, u);
}

// LayerNorm body: one wave handles one row of 256
__device__ __forceinline__ void ln_row_body(const float* __restrict__ x,
                                            const float* __restrict__ g,
                                            const float* __restrict__ b,
                                            unsigned short* __restrict__ out,
                                            int row, int lane) {
    const float4 xv = *(const float4*)(x + (size_t)row * 256 + lane * 4);
    float s  = xv.x + xv.y + xv.z + xv.w;
    float sq = xv.x*xv.x + xv.y*xv.y + xv.z*xv.z + xv.w*xv.w;
#pragma unroll
    for (int m = 1; m < 64; m <<= 1) { s += __shfl_xor(s, m); sq += __shfl_xor(sq, m); }
    float mean = s * (1.0f/256.0f);
    float var  = sq * (1.0f/256.0f) - mean*mean;
    float rstd = rsqrtf(var + EPS_);
    float4 gv = *(const float4*)(g + lane*4);
    float4 bv = *(const float4*)(b + lane*4);
    uint2 o;
    o.x = f2bf2((xv.x-mean)*rstd*gv.x + bv.x, (xv.y-mean)*rstd*gv.y + bv.y);
    o.y = f2bf2((xv.z-mean)*rstd*gv.z + bv.z, (xv.w-mean)*rstd*gv.w + bv.w);
    *(uint2*)(out + (size_t)row * 256 + lane * 4) = o;
}

// -------- prep: 0..703 weight transpose+convert; 704..767 w_proj->bf16; 768..1023 LN1 --------
__global__ __launch_bounds__(256) void prep_kernel(
    const float* __restrict__ w_qkv,  unsigned short* __restrict__ wqkvT,
    const float* __restrict__ w_mlp1, unsigned short* __restrict__ wmlp1T,
    const float* __restrict__ w_mlp2, unsigned short* __restrict__ wmlp2T,
    const float* __restrict__ w_proj, unsigned short* __restrict__ wprojbf,
    const float* __restrict__ x, const float* __restrict__ g_n1,
    const float* __restrict__ b_n1, unsigned short* __restrict__ hbf) {
    __shared__ float tile[32][33];
    int bid = blockIdx.x, t = threadIdx.x;
    if (bid >= 768) {
        ln_row_body(x, g_n1, b_n1, hbf, (bid - 768) * 4 + (t >> 6), t & 63);
        return;
    }
    if (bid >= 704) {   // w_proj f32 -> bf16 (no transpose), 64 blocks x 256 float4
        int idx = (bid - 704) * 256 + t;
        float4 v = ((const float4*)w_proj)[idx];
        uint2 o;
        o.x = f2bf2(v.x, v.y);
        o.y = f2bf2(v.z, v.w);
        *(uint2*)(wprojbf + (size_t)idx * 4) = o;
        return;
    }
    const float* W; unsigned short* WT; int K, N, tt;
    if (bid < 192)      { W = w_qkv;  WT = wqkvT;  K = 256;  N = 768;  tt = bid; }
    else if (bid < 448) { W = w_mlp1; WT = wmlp1T; K = 256;  N = 1024; tt = bid - 192; }
    else                { W = w_mlp2; WT = wmlp2T; K = 1024; N = 256;  tt = bid - 448; }
    int ntn = N >> 5;
    int kt = tt / ntn, nt = tt % ntn;
    int k0 = kt * 32, n0 = nt * 32;
    {
        int kr = t >> 3, cg = (t & 7) * 4;
        float4 v = *(const float4*)(W + (size_t)(k0 + kr) * N + n0 + cg);
        tile[kr][cg+0] = v.x; tile[kr][cg+1] = v.y; tile[kr][cg+2] = v.z; tile[kr][cg+3] = v.w;
    }
    __syncthreads();
    {
        int nr = t >> 3, kg = (t & 7) * 4;
        uint2 o;
        o.x = f2bf2(tile[kg+0][nr], tile[kg+1][nr]);
        o.y = f2bf2(tile[kg+2][nr], tile[kg+3][nr]);
        *(uint2*)(WT + (size_t)(n0 + nr) * K + k0 + kg) = o;
    }
}

// -------- bf16 MFMA GEMM (+bias)(gelu); BF16OUT; ATOMIC adds into Cout; VOUT: bf16 copy cols>=512 --------
template<bool BIAS, bool GACT, bool BF16OUT, int KSPLIT, bool ATOMIC, bool VOUT>
__global__ __launch_bounds__(256) void mgemm_kernel(
    const unsigned short* __restrict__ A, const unsigned short* __restrict__ BT,
    const float* __restrict__ bias,
    void* __restrict__ Cout, unsigned short* __restrict__ vbf, int M, int N, int K) {
    __shared__ unsigned short Al[64][40];
    __shared__ unsigned short Bl[64][40];
    int t = threadIdx.x;
    int bm = blockIdx.x, bn = blockIdx.y, kz = blockIdx.z;
    int kchunk = K / KSPLIT;
    int srow = t >> 2, skk = (t & 3) * 8;
    const unsigned short* Ap = A  + (size_t)(bm*64 + srow) * K + kz*kchunk + skk;
    const unsigned short* Bp = BT + (size_t)(bn*64 + srow) * K + kz*kchunk + skk;
    int lane = t & 63, w = t >> 6, wr = w >> 1, wc = w & 1;
    int fr = lane & 15, fg = lane >> 4;
    f32x4_t a00 = {0.f,0.f,0.f,0.f}, a01 = {0.f,0.f,0.f,0.f};
    f32x4_t a10 = {0.f,0.f,0.f,0.f}, a11 = {0.f,0.f,0.f,0.f};
    for (int kk = 0; kk < kchunk; kk += 32) {
        uint4 av = *(const uint4*)(Ap + kk);
        uint4 bv = *(const uint4*)(Bp + kk);
        __syncthreads();
        *(uint4*)&Al[srow][skk] = av;
        *(uint4*)&Bl[srow][skk] = bv;
        __syncthreads();
        bf16x8_t fa0 = *(const bf16x8_t*)&Al[wr*32      + fr][fg*8];
        bf16x8_t fa1 = *(const bf16x8_t*)&Al[wr*32 + 16 + fr][fg*8];
        bf16x8_t fb0 = *(const bf16x8_t*)&Bl[wc*32      + fr][fg*8];
        bf16x8_t fb1 = *(const bf16x8_t*)&Bl[wc*32 + 16 + fr][fg*8];
        a00 = __builtin_amdgcn_mfma_f32_16x16x32_bf16(fa0, fb0, a00, 0, 0, 0);
        a01 = __builtin_amdgcn_mfma_f32_16x16x32_bf16(fa0, fb1, a01, 0, 0, 0);
        a10 = __builtin_amdgcn_mfma_f32_16x16x32_bf16(fa1, fb0, a10, 0, 0, 0);
        a11 = __builtin_amdgcn_mfma_f32_16x16x32_bf16(fa1, fb1, a11, 0, 0, 0);
    }
    float* Cf = (float*)Cout;
    unsigned short* Cb = (unsigned short*)Cout;
    auto emit = [&](f32x4_t acc, int mi, int ni) {
        int Ro = bm*64 + wr*32 + mi*16 + fg*4;
        int Co = bn*64 + wc*32 + ni*16 + fr;
        float bval = BIAS ? bias[Co] : 0.f;
#pragma unroll
        for (int e = 0; e < 4; ++e) {
            int r = Ro + e;
            float v = acc[e];
            if (BIAS)  v += bval;
            if (GACT)  v = gelu_f(v);
            if (ATOMIC)      atomicAdd(&Cf[(size_t)r * N + Co], v);
            else if (BF16OUT) Cb[(size_t)r * N + Co] = f2bf(v);
            else              Cf[(size_t)r * N + Co] = v;
            if (VOUT && Co >= 512) vbf[(size_t)r * 256 + (Co - 512)] = f2bf(v);
        }
    };
    emit(a00, 0, 0); emit(a01, 0, 1); emit(a10, 1, 0); emit(a11, 1, 1);
}

// -------- qk[bi][h][j] (bf16) from bf16 qkv; block = (i-tile 32, h, b), k staged f32 in LDS --------
__global__ __launch_bounds__(256) void qk_kernel(const unsigned short* __restrict__ qkv,
                                                 unsigned short* __restrict__ qk) {
    __shared__ float k_lds[512*32];   // 64 KB
    int t = threadIdx.x;
    int it = blockIdx.x;              // 0..15
    int h  = blockIdx.y;              // 0..7
    int b  = blockIdx.z;              // 0..1
    const unsigned short* base = qkv + (size_t)b * 393216;
#pragma unroll
    for (int r = 0; r < 16; ++r) {
        int idx = r*256 + t;
        int row = idx >> 3, c4 = idx & 7;
        ushort4 kv = *(const ushort4*)(base + (size_t)row*768 + 256 + h*32 + c4*4);
        float4 f = make_float4(bf2f(kv.x), bf2f(kv.y), bf2f(kv.z), bf2f(kv.w));
        *(float4*)(k_lds + row*32 + c4*4) = f;
    }
    __syncthreads();
    int ir = t & 31, jg = t >> 5;
    int i = it*32 + ir;
    float4 q[8];
    const unsigned short* qp = base + (size_t)i*768 + h*32;
#pragma unroll
    for (int c4 = 0; c4 < 8; ++c4) {
        ushort4 qv = *(const ushort4*)(qp + c4*4);
        q[c4] = make_float4(bf2f(qv.x), bf2f(qv.y), bf2f(qv.z), bf2f(qv.w));
    }
    unsigned short* outp = qk + (((size_t)(b*512 + i))*8 + h)*512 + jg*64;
    for (int jj = 0; jj < 64; jj += 4) {
        float a4[4];
#pragma unroll
        for (int u = 0; u < 4; ++u) {
            const float* kp = k_lds + (size_t)(jg*64 + jj + u)*32;
            float acc = 0.f;
#pragma unroll
            for (int c4 = 0; c4 < 8; ++c4) {
                float4 kv = *(const float4*)(kp + c4*4);
                acc += q[c4].x*kv.x + q[c4].y*kv.y + q[c4].z*kv.z + q[c4].w*kv.w;
            }
            a4[u] = acc;
        }
        uint2 o2;
        o2.x = f2bf2(a4[0], a4[1]);
        o2.y = f2bf2(a4[2], a4[3]);
        *(uint2*)(outp + jj) = o2;
    }
}

// -------- MEGA (1 row/block): rel-MFMA + GELU/LN + softmax + attn@v + proj + resid + LN2 --------
// Writes out = x1 + b_mlp2 and h2 = LN2(x1) bf16. v and w_proj read as bf16.
#define LGS 520
__global__ __launch_bounds__(256) void rel_mega_kernel(
    const float* __restrict__ rp, const unsigned short* __restrict__ qk,
    const unsigned short* __restrict__ vbf,
    const float* __restrict__ w_rel, const float* __restrict__ b_rel,
    const float* __restrict__ g_reln, const float* __restrict__ b_reln,
    const unsigned short* __restrict__ wprojbf, const float* __restrict__ b_proj,
    const float* __restrict__ x, const float* __restrict__ g_n2,
    const float* __restrict__ b_n2, const float* __restrict__ b_mlp2,
    float* __restrict__ out, unsigned short* __restrict__ h2bf) {
    __shared__ float lg_lds[8*LGS];   // 16.6 KB
    __shared__ float o_lds[256];
    __shared__ float red[8];
    int t = threadIdx.x;
    int bi = blockIdx.x;              // b*512 + i
    int b  = bi >> 9;
    int wid = t >> 6, lane = t & 63;
    int fr = lane & 15, fg = lane >> 4;
    bool act = fr < 8;
    // ---- phase A: w_rel B fragments (zero-padded h>=8) ----
    bf16x8_t bfrag[8];
#pragma unroll
    for (int kk = 0; kk < 8; ++kk) {
        bf16x8_t bf;
#pragma unroll
        for (int e = 0; e < 8; ++e) {
            float v = act ? w_rel[(size_t)(kk*32 + fg*8 + e)*8 + fr] : 0.f;
            bf[e] = (short)f2bf(v);
        }
        bfrag[kk] = bf;
    }
    const float* rpb = rp + (size_t)bi * 512 * 256;
    // ---- phase B: rel MFMA, raw sums to LDS (unroll 2: compiler software-pipelines tiles) ----
#pragma unroll 2
    for (int tile = 0; tile < 8; ++tile) {
        int j0 = wid*128 + tile*16;
        const float* arow = rpb + (size_t)(j0 + fr)*256 + fg*8;
        f32x4_t acc = {0.f,0.f,0.f,0.f};
#pragma unroll
        for (int kk = 0; kk < 8; ++kk) {
            float4 x0 = *(const float4*)(arow + kk*32);
            float4 x1 = *(const float4*)(arow + kk*32 + 4);
            union { bf16x8_t v; uint4 u; } cvt;
            cvt.u.x = f2bf2(x0.x, x0.y);
            cvt.u.y = f2bf2(x0.z, x0.w);
            cvt.u.z = f2bf2(x1.x, x1.y);
            cvt.u.w = f2bf2(x1.z, x1.w);
            acc = __builtin_amdgcn_mfma_f32_16x16x32_bf16(cvt.v, bfrag[kk], acc, 0, 0, 0);
        }
        if (act) {
#pragma unroll
            for (int r = 0; r < 4; ++r)
                lg_lds[fr*LGS + j0 + fg*4 + r] = acc[r];
        }
    }
    __syncthreads();
    // ---- phase C0: GELU + LayerNorm over H=8, fully in-lane ----
#pragma unroll
    for (int rep = 0; rep < 2; ++rep) {
        int j = t + rep*256;
        float gv[8];
        float sm = 0.f, sq = 0.f;
#pragma unroll
        for (int h = 0; h < 8; ++h) {
            float val = lg_lds[h*LGS + j] + b_rel[h];
            float g = gelu_f(val);
            gv[h] = g; sm += g; sq += g*g;
        }
        float mean = sm * 0.125f;
        float var  = sq * 0.125f - mean*mean;
        float rstd = rsqrtf(var + EPS_);
#pragma unroll
        for (int h = 0; h < 8; ++h)
            lg_lds[h*LGS + j] = (gv[h] - mean) * rstd * g_reln[h] + b_reln[h];
    }
    __syncthreads();
    // ---- phase C: softmax (half-wave per head row), probs kept in LDS ----
    {
        int h = wid*2 + (lane >> 5);
        int sub = lane & 31;
        float* row = lg_lds + h*LGS;
        const unsigned short* qrow = qk + ((size_t)bi*8 + h)*512;
        float v[16];
#pragma unroll
        for (int c4 = 0; c4 < 4; ++c4) {
            float4 r4 = *(const float4*)(row + c4*128 + sub*4);
            ushort4 q4 = *(const ushort4*)(qrow + c4*128 + sub*4);
            v[c4*4+0] = (bf2f(q4.x) + r4.x) * SCALE_;
            v[c4*4+1] = (bf2f(q4.y) + r4.y) * SCALE_;
            v[c4*4+2] = (bf2f(q4.z) + r4.z) * SCALE_;
            v[c4*4+3] = (bf2f(q4.w) + r4.w) * SCALE_;
        }
        float mx = v[0];
#pragma unroll
        for (int e = 1; e < 16; ++e) mx = fmaxf(mx, v[e]);
#pragma unroll
        for (int m = 1; m < 32; m <<= 1) mx = fmaxf(mx, __shfl_xor(mx, m));
        float s = 0.f;
#pragma unroll
        for (int e = 0; e < 16; ++e) { v[e] = __expf(v[e] - mx); s += v[e]; }
#pragma unroll
        for (int m = 1; m < 32; m <<= 1) s += __shfl_xor(s, m);
        float inv = 1.0f / s;
#pragma unroll
        for (int e = 0; e < 16; ++e) v[e] *= inv;
#pragma unroll
        for (int c4 = 0; c4 < 4; ++c4) {
            float4 o4 = make_float4(v[c4*4+0], v[c4*4+1], v[c4*4+2], v[c4*4+3]);
            *(float4*)(row + c4*128 + sub*4) = o4;
        }
    }
    __syncthreads();
    // ---- phase D: o[c] = sum_j probs[h(c)][j] * v[j][c]  (v bf16, coalesced over c) ----
    {
        int c = t, h = c >> 5;
        const unsigned short* vcol = vbf + (size_t)b*131072 + c;
        const float* arow = lg_lds + h*LGS;
        float acc = 0.f;
        for (int j = 0; j < 512; j += 4) {
            float4 a4 = *(const float4*)(arow + j);
            acc += a4.x * bf2f(vcol[(size_t)(j+0)*256]);
            acc += a4.y * bf2f(vcol[(size_t)(j+1)*256]);
            acc += a4.z * bf2f(vcol[(size_t)(j+2)*256]);
            acc += a4.w * bf2f(vcol[(size_t)(j+3)*256]);
        }
        o_lds[c] = acc;
    }
    __syncthreads();
    // ---- phase E: proj (bf16 weights) + bias + residual -> x1; out = x1 + b_mlp2 ----
    float x1c;
    {
        int c = t;
        float acc2 = 0.f;
        for (int k = 0; k < 256; k += 4) {
            acc2 += o_lds[k+0] * bf2f(wprojbf[(size_t)(k+0)*256 + c]);
            acc2 += o_lds[k+1] * bf2f(wprojbf[(size_t)(k+1)*256 + c]);
            acc2 += o_lds[k+2] * bf2f(wprojbf[(size_t)(k+2)*256 + c]);
            acc2 += o_lds[k+3] * bf2f(wprojbf[(size_t)(k+3)*256 + c]);
        }
        x1c = x[(size_t)bi*256 + c] + b_proj[c] + acc2;
        out[(size_t)bi*256 + c] = x1c + b_mlp2[c];
    }
    // ---- phase F: LN2 (block reduce over 256) -> h2 bf16 ----
    {
        float s = x1c, sq = x1c*x1c;
#pragma unroll
        for (int m = 1; m < 64; m <<= 1) { s += __shfl_xor(s, m); sq += __shfl_xor(sq, m); }
        if (lane == 0) { red[wid*2] = s; red[wid*2+1] = sq; }
        __syncthreads();
        float S  = red[0] + red[2] + red[4] + red[6];
        float SQ = red[1] + red[3] + red[5] + red[7];
        float mean = S * (1.0f/256.0f);
        float var  = SQ * (1.0f/256.0f) - mean*mean;
        float rstd = rsqrtf(var + EPS_);
        float h2 = (x1c - mean) * rstd * g_n2[t] + b_n2[t];
        h2bf[(size_t)bi*256 + t] = f2bf(h2);
    }
}

extern "C" void kernel_launch(void* const* d_in, const int* in_sizes, int n_in,
                              void* d_out, int out_size, void* d_ws, size_t ws_size,
                              hipStream_t stream) {
    const float* x      = (const float*)d_in[0];
    const float* rp     = (const float*)d_in[1];
    const float* w_qkv  = (const float*)d_in[2];
    const float* w_proj = (const float*)d_in[3];
    const float* b_proj = (const float*)d_in[4];
    const float* w_rel  = (const float*)d_in[5];
    const float* b_rel  = (const float*)d_in[6];
    const float* g_reln = (const float*)d_in[7];
    const float* b_reln = (const float*)d_in[8];
    const float* g_n1   = (const float*)d_in[9];
    const float* b_n1   = (const float*)d_in[10];
    const float* g_n2   = (const float*)d_in[11];
    const float* b_n2   = (const float*)d_in[12];
    const float* w_mlp1 = (const float*)d_in[13];
    const float* b_mlp1 = (const float*)d_in[14];
    const float* w_mlp2 = (const float*)d_in[15];
    const float* b_mlp2 = (const float*)d_in[16];
    float* out = (float*)d_out;

    unsigned short* ub = (unsigned short*)d_ws;
    unsigned short* qkvbf   = ub;               // 786432  bf16 [1024][768]
    unsigned short* qkbf    = qkvbf + 786432;   // 4194304 bf16 [bi][h][j]
    unsigned short* vbf     = qkbf + 4194304;   // 262144  bf16 [bi][c]
    unsigned short* hbf     = vbf  + 262144;    // 262144  bf16 (LN1 out)
    unsigned short* h2bf    = hbf  + 262144;    // 262144  bf16 (LN2 out)
    unsigned short* hgbf    = h2bf + 262144;    // 1048576 bf16 (mlp1 out)
    unsigned short* wqkvT   = hgbf + 1048576;   // 196608
    unsigned short* wmlp1T  = wqkvT + 196608;   // 262144
    unsigned short* wmlp2T  = wmlp1T + 262144;  // 262144
    unsigned short* wprojbf = wmlp2T + 262144;  // 65536

    // 0) weights -> bf16 (T for gemms, plain for proj), and h = LN1(x)
    prep_kernel<<<1024, 256, 0, stream>>>(w_qkv, wqkvT, w_mlp1, wmlp1T, w_mlp2, wmlp2T,
                                          w_proj, wprojbf, x, g_n1, b_n1, hbf);
    // 1) qkv = h @ w_qkv [1024,768] bf16; v columns also emitted compact -> vbf
    mgemm_kernel<false,false,true,1,false,true><<<dim3(16,12,1), 256, 0, stream>>>(
        hbf, wqkvT, nullptr, qkvbf, vbf, 1024, 768, 256);
    // 2) qk[bi][h][j] (bf16)
    qk_kernel<<<dim3(16,8,2), 256, 0, stream>>>(qkvbf, qkbf);
    // 3) MEGA: attn probs + attn@v + proj + resid + LN2; out = x1 + b_mlp2
    rel_mega_kernel<<<1024, 256, 0, stream>>>(rp, qkbf, vbf, w_rel, b_rel,
                                              g_reln, b_reln, wprojbf, b_proj,
                                              x, g_n2, b_n2, b_mlp2, out, h2bf);
    // 4) hg = GELU(h2 @ w_mlp1 + b_mlp1)  [1024,1024] bf16
    mgemm_kernel<true,true,true,1,false,false><<<dim3(16,16,1), 256, 0, stream>>>(
        h2bf, wmlp1T, b_mlp1, hgbf, nullptr, 1024, 1024, 256);
    // 5) out += hg @ w_mlp2 (split-K=4, atomic partials)
    mgemm_kernel<false,false,false,4,true,false><<<dim3(16,4,4), 256, 0, stream>>>(
        hgbf, wmlp2T, nullptr, out, nullptr, 1024, 256, 1024);
}